// Round 1
// baseline (59.791 us; speedup 1.0000x reference)
//
#include <hip/hip_runtime.h>
#include <math.h>

#define FEAT 64

// One 64-lane wave per destination node; lane = feature index.
// Softmax over the node's edges (uniform degree 16 fast path), then
// weighted gather-accumulate of node_value rows.
__global__ __launch_bounds__(256) void gat_agg_kernel(
    const void* __restrict__ row_ptr_v,
    const void* __restrict__ col_idx_v,
    const float* __restrict__ scores,
    const float* __restrict__ values,
    float* __restrict__ out,
    int num_nodes)
{
    const int wid  = blockIdx.x * (blockDim.x >> 6) + (threadIdx.x >> 6);
    const int lane = threadIdx.x & 63;
    if (wid >= num_nodes) return;

    // Detect index width at runtime: row_ptr[1] == DEGREE (>0) for int32;
    // for an int64 buffer the second 32-bit word is hi(row_ptr[0]) == 0.
    const int* rp32 = (const int*)row_ptr_v;
    const bool idx64 = (rp32[1] == 0);

    long long start, end;
    if (idx64) {
        const long long* rp = (const long long*)row_ptr_v;
        start = rp[wid];
        end   = rp[wid + 1];
    } else {
        start = (long long)rp32[wid];
        end   = (long long)rp32[wid + 1];
    }
    const int deg = (int)(end - start);

    if (deg <= 0) {
        out[(long long)wid * FEAT + lane] = 0.0f;
        return;
    }

    float acc = 0.0f;

    if (deg == 16 && ((start & 3) == 0) && !idx64) {
        // ---- fast path: uniform degree 16, int32 indices ----
        const float4* sv = (const float4*)(scores + start);
        float4 s0 = sv[0], s1 = sv[1], s2 = sv[2], s3 = sv[3];
        float s[16] = { s0.x, s0.y, s0.z, s0.w,
                        s1.x, s1.y, s1.z, s1.w,
                        s2.x, s2.y, s2.z, s2.w,
                        s3.x, s3.y, s3.z, s3.w };

        float m = s[0];
        #pragma unroll
        for (int k = 1; k < 16; ++k) m = fmaxf(m, s[k]);

        float sum = 0.0f;
        #pragma unroll
        for (int k = 0; k < 16; ++k) { s[k] = __expf(s[k] - m); sum += s[k]; }
        const float inv = 1.0f / sum;

        const int4* cv = (const int4*)((const int*)col_idx_v + start);
        int4 c0 = cv[0], c1 = cv[1], c2 = cv[2], c3 = cv[3];
        int cols[16] = { c0.x, c0.y, c0.z, c0.w,
                         c1.x, c1.y, c1.z, c1.w,
                         c2.x, c2.y, c2.z, c2.w,
                         c3.x, c3.y, c3.z, c3.w };

        #pragma unroll
        for (int k = 0; k < 16; ++k) {
            acc += s[k] * values[(long long)cols[k] * FEAT + lane];
        }
        acc *= inv;
    } else {
        // ---- generic fallback: any degree, either index width ----
        float m = -INFINITY;
        for (long long e = start; e < end; ++e) m = fmaxf(m, scores[e]);
        float sum = 0.0f;
        for (long long e = start; e < end; ++e) sum += __expf(scores[e] - m);
        const float inv = 1.0f / sum;
        for (long long e = start; e < end; ++e) {
            long long c = idx64 ? ((const long long*)col_idx_v)[e]
                                : (long long)((const int*)col_idx_v)[e];
            acc += __expf(scores[e] - m) * values[c * FEAT + lane];
        }
        acc *= inv;
    }

    out[(long long)wid * FEAT + lane] = acc;
}

extern "C" void kernel_launch(void* const* d_in, const int* in_sizes, int n_in,
                              void* d_out, int out_size, void* d_ws, size_t ws_size,
                              hipStream_t stream) {
    const void*  row_ptr = d_in[0];
    const void*  col_idx = d_in[1];
    const float* scores  = (const float*)d_in[2];
    const float* values  = (const float*)d_in[3];
    float*       out     = (float*)d_out;

    const int num_nodes = in_sizes[0] - 1;           // 100000
    const int waves_per_block = 256 / 64;            // 4 nodes per block
    const int blocks = (num_nodes + waves_per_block - 1) / waves_per_block;

    hipLaunchKernelGGL(gat_agg_kernel, dim3(blocks), dim3(256), 0, stream,
                       row_ptr, col_idx, scores, values, out, num_nodes);
}